// Round 6
// baseline (6007.427 us; speedup 1.0000x reference)
//
#include <hip/hip_runtime.h>
#include <hip/hip_bf16.h>

typedef unsigned short u16;
typedef __hip_bfloat16 bf16;

#define B_   128
#define N_   197
#define C_   768
#define H_   12
#define HD_  64
#define T_   (B_*N_)      // 25216 rows
#define MH_  3072
#define OUT_ 32
#define CN_  196
#define CHH_ 14

__device__ __forceinline__ float bfu2f(u16 x){ union{unsigned u; float f;} v; v.u=((unsigned)x)<<16; return v.f; }
__device__ __forceinline__ bf16  f2bf(float f){ return __float2bfloat16(f); }
__device__ __forceinline__ float gelu_f(float x){ return 0.5f*x*(1.0f+erff(x*0.70710678118654752f)); }

__global__ __launch_bounds__(256) void write_code_kernel(float* out, int n, float code){
  int i = blockIdx.x*256 + threadIdx.x;
  if (i < n) out[i] = code;
}

// ---------------- LayerNorm over 768 (fp32 or bf16 in -> bf16 out) ----------------
template<bool F32IN>
__global__ __launch_bounds__(256) void ln768_kernel(const void* __restrict__ xv,
    const float* __restrict__ g, const float* __restrict__ b, bf16* __restrict__ out)
{
  int row = blockIdx.x;
  int tid = threadIdx.x;
  float v0, v1, v2;
  if (F32IN){
    const float* xr = (const float*)xv + (size_t)row*C_;
    v0 = xr[tid]; v1 = xr[tid+256]; v2 = xr[tid+512];
  } else {
    const u16* xr = (const u16*)xv + (size_t)row*C_;
    v0 = bfu2f(xr[tid]); v1 = bfu2f(xr[tid+256]); v2 = bfu2f(xr[tid+512]);
  }
  __shared__ float red[4];
  int lane = tid & 63, wave = tid >> 6;
  float s = v0+v1+v2;
  #pragma unroll
  for (int off=32; off>0; off>>=1) s += __shfl_xor(s, off);
  if (lane==0) red[wave]=s;
  __syncthreads();
  float mean = (red[0]+red[1]+red[2]+red[3]) * (1.0f/C_);
  float d0=v0-mean, d1=v1-mean, d2=v2-mean;
  float q = d0*d0+d1*d1+d2*d2;
  #pragma unroll
  for (int off=32; off>0; off>>=1) q += __shfl_xor(q, off);
  __syncthreads();
  if (lane==0) red[wave]=q;
  __syncthreads();
  float var = (red[0]+red[1]+red[2]+red[3]) * (1.0f/C_);
  float r = rsqrtf(var + 1e-5f);
  bf16* orow = out + (size_t)row*C_;
  orow[tid]     = f2bf(d0*r*g[tid]     + b[tid]);
  orow[tid+256] = f2bf(d1*r*g[tid+256] + b[tid+256]);
  orow[tid+512] = f2bf(d2*r*g[tid+512] + b[tid+512]);
}

// ---------------- LayerNorm over 32 (f32 in -> f32 out) ----------------
__global__ __launch_bounds__(256) void ln32_kernel(const float* __restrict__ x,
    const float* __restrict__ g, const float* __restrict__ b, float* __restrict__ out)
{
  int i = blockIdx.x*256 + threadIdx.x;
  int c = i & 31;
  float v = x[i];
  float s = v;
  #pragma unroll
  for (int off=16; off>0; off>>=1) s += __shfl_xor(s, off, 32);
  float mean = s * (1.0f/32);
  float d = v - mean;
  float q = d*d;
  #pragma unroll
  for (int off=16; off>0; off>>=1) q += __shfl_xor(q, off, 32);
  float r = rsqrtf(q*(1.0f/32) + 1e-5f);
  out[i] = d*r*g[c] + b[c];
}

// ---------------- Tiled GEMM: out[M,N] = A[M,K](bf16) @ W[N,K'](f32)^T ---------
// MODE 0: scatter to q/k/v (B,H,N,64) bf16
// MODE 1: + bias + resid(f32) -> bf16
// MODE 2: gelu(+bias)    -> bf16
// MODE 3: + bias         -> f32 write
// MODE 4: accumulate     -> f32 +=
#define BM 64
#define BN 64
#define BK 16
template<int MODE>
__global__ __launch_bounds__(256) void gemm_bt(
    const u16* __restrict__ A, const float* __restrict__ W,
    const float* __restrict__ bias, const float* __restrict__ resid,
    float* __restrict__ outf, bf16* __restrict__ outb,
    bf16* __restrict__ q_out, bf16* __restrict__ k_out, bf16* __restrict__ v_out,
    int M, int Nn, int K, int wld)
{
  __shared__ __align__(16) float As[BK][BM];
  __shared__ __align__(16) float Ws[BK][BN];
  const int tid = threadIdx.x;
  const int m0 = blockIdx.x * BM;
  const int n0 = blockIdx.y * BN;
  const int tx = tid & 15;
  const int ty = tid >> 4;
  const int lr = tid >> 2;
  const int lc = (tid & 3) << 2;
  float acc[4][4] = {};
  const u16* ap = A + (size_t)(m0+lr)*K + lc;
  const bool wvalid = (n0 + lr) < Nn;
  const float* wp = W + (size_t)(n0+lr)*wld + lc;
  for (int k0=0; k0<K; k0+=BK){
    ushort4 av = *(const ushort4*)(ap + k0);
    As[lc+0][lr] = bfu2f(av.x);
    As[lc+1][lr] = bfu2f(av.y);
    As[lc+2][lr] = bfu2f(av.z);
    As[lc+3][lr] = bfu2f(av.w);
    float4 wv = make_float4(0.f,0.f,0.f,0.f);
    if (wvalid) wv = *(const float4*)(wp + k0);
    Ws[lc+0][lr] = wv.x;
    Ws[lc+1][lr] = wv.y;
    Ws[lc+2][lr] = wv.z;
    Ws[lc+3][lr] = wv.w;
    __syncthreads();
    #pragma unroll
    for (int kk=0; kk<BK; kk++){
      float4 a = *(const float4*)&As[kk][ty<<2];
      float4 w = *(const float4*)&Ws[kk][tx<<2];
      float av_[4] = {a.x,a.y,a.z,a.w};
      float wv_[4] = {w.x,w.y,w.z,w.w};
      #pragma unroll
      for (int i=0;i<4;i++)
        #pragma unroll
        for (int j=0;j<4;j++)
          acc[i][j] += av_[i]*wv_[j];
    }
    __syncthreads();
  }
  #pragma unroll
  for (int i=0;i<4;i++){
    int m = m0 + (ty<<2) + i;
    int bb = m / N_;
    int n  = m - bb*N_;
    #pragma unroll
    for (int j=0;j<4;j++){
      int c = n0 + (tx<<2) + j;
      if (c >= Nn) continue;
      float v = acc[i][j];
      if (MODE==0){
        int sec = c / C_;
        int rem = c - sec*C_;
        int hh  = rem >> 6;
        int d   = rem & 63;
        bf16* dst = (sec==0) ? q_out : (sec==1) ? k_out : v_out;
        dst[(((size_t)bb*H_ + hh)*N_ + n)*HD_ + d] = f2bf(v);
      } else if (MODE==1){
        size_t idx = (size_t)m*Nn + c;
        outb[idx] = f2bf(v + bias[c] + resid[idx]);
      } else if (MODE==2){
        outb[(size_t)m*Nn + c] = f2bf(gelu_f(v + bias[c]));
      } else if (MODE==3){
        outf[(size_t)m*Nn + c] = v + bias[c];
      } else {
        outf[(size_t)m*Nn + c] += v;
      }
    }
  }
}

// ---------------- Fused attention: one block per (b,h) ----------------
__global__ __launch_bounds__(256) void attn_kernel(const u16* __restrict__ q,
    const u16* __restrict__ k, const u16* __restrict__ v, bf16* __restrict__ o)
{
  __shared__ __align__(16) u16 Ks[N_*66];
  __shared__ __align__(16) u16 Vs[N_*66];
  __shared__ __align__(16) float qs[4][64];
  __shared__ __align__(16) float ps[4][208];
  int bh = blockIdx.x;
  int b  = bh / H_;
  int hh = bh - b*H_;
  int tid = threadIdx.x;
  const u16* kb = k + (size_t)bh*N_*HD_;
  const u16* vb = v + (size_t)bh*N_*HD_;
  for (int idx=tid; idx<N_*HD_; idx+=256){
    int j = idx >> 6, d = idx & 63;
    Ks[j*66+d] = kb[idx];
    Vs[j*66+d] = vb[idx];
  }
  __syncthreads();
  int wave = tid>>6, lane = tid&63;
  const u16* qb = q + (size_t)bh*N_*HD_;
  for (int qi=wave; qi<N_; qi+=4){
    qs[wave][lane] = bfu2f(qb[qi*HD_+lane]);
    float sc[4];
    #pragma unroll
    for (int t=0;t<4;t++){
      int j = lane + (t<<6);
      float a = 0.f;
      if (j < N_){
        const u16* kr = &Ks[j*66];
        #pragma unroll
        for (int d=0; d<64; d+=2){
          unsigned pk = *(const unsigned*)&kr[d];
          a += qs[wave][d]   * bfu2f((u16)(pk & 0xffffu));
          a += qs[wave][d+1] * bfu2f((u16)(pk >> 16));
        }
      }
      sc[t] = a * 0.125f;
    }
    float mx = -1e30f;
    #pragma unroll
    for (int t=0;t<4;t++) if (lane+(t<<6) < N_) mx = fmaxf(mx, sc[t]);
    #pragma unroll
    for (int off=32; off>0; off>>=1) mx = fmaxf(mx, __shfl_xor(mx, off));
    float sum = 0.f;
    #pragma unroll
    for (int t=0;t<4;t++) if (lane+(t<<6) < N_){ sc[t] = expf(sc[t]-mx); sum += sc[t]; }
    #pragma unroll
    for (int off=32; off>0; off>>=1) sum += __shfl_xor(sum, off);
    float inv = 1.0f/sum;
    #pragma unroll
    for (int t=0;t<4;t++){ int j = lane+(t<<6); if (j < N_) ps[wave][j] = sc[t]*inv; }
    float acc = 0.f;
    for (int j=0;j<N_;j++) acc += ps[wave][j] * bfu2f(Vs[j*66+lane]);
    o[((size_t)b*N_ + qi)*C_ + hh*HD_ + lane] = f2bf(acc);
  }
}

// ---------------- channel qkv: per b, (32x196) @ (588x196)^T, scatter ----------
__global__ __launch_bounds__(256) void cqkv_kernel(const float* __restrict__ h3,
    const float* __restrict__ w, float* __restrict__ cq, float* __restrict__ ck,
    float* __restrict__ cv)
{
  __shared__ __align__(16) float ts[32*201];
  int b = blockIdx.x, tid = threadIdx.x;
  for (int idx=tid; idx<CN_*32; idx+=256){
    int n = idx >> 5, o = idx & 31;
    ts[o*201+n] = h3[((size_t)b*N_ + 1 + n)*32 + o];
  }
  __syncthreads();
  for (int idx=tid; idx<32*588; idx+=256){
    int o = idx / 588, j = idx - o*588;
    const float* wr = w + (size_t)j*CN_;
    float acc = 0.f;
    for (int kk=0; kk<CN_; kk++) acc += ts[o*201+kk] * wr[kk];
    int sec = j / CN_;
    int rem = j - sec*CN_;
    int hh  = rem / 14;
    int d   = rem - hh*14;
    float* dst = (sec==0) ? cq : (sec==1) ? ck : cv;
    dst[(((size_t)b*CHH_ + hh)*32 + o)*14 + d] = acc;
  }
}

// ---------------- channel attention: one wave per (b,head) ----------------
__global__ __launch_bounds__(64) void cattn_kernel(const float* __restrict__ cq,
    const float* __restrict__ ck, const float* __restrict__ cv, float* __restrict__ co)
{
  __shared__ __align__(16) float qs[32*15], ks_[32*15], vs[32*15], ps[32*34];
  int bh = blockIdx.x;
  int b  = bh / CHH_;
  int hh = bh - b*CHH_;
  int lane = threadIdx.x;
  const float* qb = cq + (size_t)bh*448;
  const float* kb = ck + (size_t)bh*448;
  const float* vb = cv + (size_t)bh*448;
  for (int idx=lane; idx<448; idx+=64){
    int o = idx/14, d = idx - o*14;
    qs[o*15+d] = qb[idx]; ks_[o*15+d] = kb[idx]; vs[o*15+d] = vb[idx];
  }
  __syncthreads();
  int o = lane & 31, half = lane >> 5;
  const float scale = 0.2672612419124244f;
  float sc[16]; float mx = -1e30f;
  #pragma unroll
  for (int jj=0; jj<16; jj++){
    int j = half*16 + jj;
    float a = 0.f;
    #pragma unroll
    for (int d=0; d<14; d++) a += qs[o*15+d]*ks_[j*15+d];
    sc[jj] = a*scale;
    mx = fmaxf(mx, sc[jj]);
  }
  mx = fmaxf(mx, __shfl_xor(mx, 32));
  float sum = 0.f;
  #pragma unroll
  for (int jj=0; jj<16; jj++){ sc[jj] = expf(sc[jj]-mx); sum += sc[jj]; }
  sum += __shfl_xor(sum, 32);
  float inv = 1.0f/sum;
  #pragma unroll
  for (int jj=0; jj<16; jj++) ps[o*34 + half*16 + jj] = sc[jj]*inv;
  __syncthreads();
  #pragma unroll
  for (int dd=0; dd<7; dd++){
    int d = half*7 + dd;
    float acc = 0.f;
    #pragma unroll
    for (int j=0; j<32; j++) acc += ps[o*34+j]*vs[j*15+d];
    co[((size_t)b*32 + o)*CN_ + hh*14 + d] = acc;
  }
}

// ---------------- channel proj: per b, (32x196) @ (196x196)^T + bias ----------
__global__ __launch_bounds__(256) void cproj_kernel(const float* __restrict__ co,
    const float* __restrict__ w, const float* __restrict__ bias, float* __restrict__ co2)
{
  __shared__ __align__(16) float cs[32*201];
  int b = blockIdx.x, tid = threadIdx.x;
  for (int idx=tid; idx<32*CN_; idx+=256){
    int o = idx / CN_, n = idx - o*CN_;
    cs[o*201+n] = co[(size_t)b*32*CN_ + idx];
  }
  __syncthreads();
  for (int idx=tid; idx<32*CN_; idx+=256){
    int o = idx / CN_, j = idx - o*CN_;
    const float* wr = w + (size_t)j*CN_;
    float acc = bias[j];
    for (int kk=0; kk<CN_; kk++) acc += cs[o*201+kk]*wr[kk];
    co2[(size_t)b*32*CN_ + o*CN_ + j] = acc;
  }
}

// ---------------- x4 = x3 + concat([cls(h3), co2^T]) ----------------
__global__ __launch_bounds__(256) void concat_add_kernel(const float* __restrict__ x3,
    const float* __restrict__ h3, const float* __restrict__ co2, float* __restrict__ x4)
{
  int i = blockIdx.x*256 + threadIdx.x;
  int c = i & 31;
  int row = i >> 5;
  int b = row / N_;
  int r = row - b*N_;
  float add = (r==0) ? h3[i] : co2[((size_t)b*32 + c)*CN_ + (r-1)];
  x4[i] = x3[i] + add;
}

// ---------------- cfc1: gelu(h4 @ w^T + b), K=32 -> 128 ----------------
__global__ __launch_bounds__(256) void cfc1_kernel(const float* __restrict__ h4,
    const float* __restrict__ w, const float* __restrict__ bias, float* __restrict__ chid)
{
  int idx = blockIdx.x*256 + threadIdx.x;
  int m = idx >> 7, j = idx & 127;
  const float* hr = h4 + (size_t)m*32;
  const float* wr = w + (size_t)j*32;
  float acc = bias[j];
  #pragma unroll
  for (int kk=0; kk<32; kk++) acc += hr[kk]*wr[kk];
  chid[idx] = gelu_f(acc);
}

// ---------------- cfc2: out = x4 + chid @ w^T + b, K=128 -> 32, FP32 out -------
__global__ __launch_bounds__(256) void cfc2_kernel(const float* __restrict__ chid,
    const float* __restrict__ w, const float* __restrict__ bias,
    const float* __restrict__ x4, float* __restrict__ out)
{
  int idx = blockIdx.x*256 + threadIdx.x;
  int m = idx >> 5, j = idx & 31;
  const float* cr = chid + (size_t)m*128;
  const float* wr = w + (size_t)j*128;
  float acc = bias[j];
  #pragma unroll
  for (int kk=0; kk<128; kk++) acc += cr[kk]*wr[kk];
  out[idx] = x4[idx] + acc;   // fp32 output (reference output dtype)
}

extern "C" void kernel_launch(void* const* d_in, const int* in_sizes, int n_in,
                              void* d_out, int out_size, void* d_ws, size_t ws_size,
                              hipStream_t stream)
{
  const int NIN = 23;
  static const int dsz[NIN] = {19365888,768,768,1769472,589824,768,768,768,2359296,
                               3072,98304,32,32,32,115248,38416,196,32,32,4096,128,4096,32};
  static const int a2d[NIN] = {2,7,13,18,20,22,16,9,11,5,1,6,12,17,19,21,15,14,8,10,4,3,0};

  float* dout = (float*)d_out;
  int ogrid = (out_size + 255)/256;

  const float* in[NIN];
  bool dict_ok = (n_in == NIN);
  if (dict_ok) for (int i=0;i<NIN;i++) if (in_sizes[i] != dsz[i]) { dict_ok=false; break; }
  if (dict_ok){
    for (int i=0;i<NIN;i++) in[i] = (const float*)d_in[i];
  } else {
    bool alpha_ok = (n_in == NIN);
    if (alpha_ok) for (int i=0;i<NIN;i++) if (in_sizes[i] != dsz[a2d[i]]) { alpha_ok=false; break; }
    if (alpha_ok){
      for (int i=0;i<NIN;i++) in[a2d[i]] = (const float*)d_in[i];
    } else {
      write_code_kernel<<<ogrid, 256, 0, stream>>>(dout, out_size, 5000.f + (float)n_in);
      return;
    }
  }

  const float* x      = in[0];
  const float* g1     = in[1];
  const float* b1     = in[2];
  const float* w_qkv  = in[3];
  const float* w_proj = in[4];
  const float* b_proj = in[5];
  const float* g2     = in[6];
  const float* b2     = in[7];
  const float* w_fc1  = in[8];
  const float* b_fc1  = in[9];
  const float* w_fc2  = in[10];
  const float* b_fc2  = in[11];
  const float* g3     = in[12];
  const float* b3     = in[13];
  const float* w_cqkv = in[14];
  const float* w_cproj= in[15];
  const float* b_cproj= in[16];
  const float* g4     = in[17];
  const float* b4     = in[18];
  const float* w_cfc1 = in[19];
  const float* b_cfc1 = in[20];
  const float* w_cfc2 = in[21];
  const float* b_cfc2 = in[22];

  char* ws = (char*)d_ws;
  const size_t TC2 = (size_t)T_*C_*2;          // 38,731,776 B
  const size_t NEED = 4*TC2 + 4096;
  if (ws_size < NEED){
    write_code_kernel<<<ogrid, 256, 0, stream>>>(dout, out_size,
        7000.f + (float)(ws_size >> 20));
    return;
  }

  // -------- workspace layout, peak 4*TC2 ~= 148 MB (bf16 intermediates) --------
  bf16* h_buf   = (bf16*)(ws);                 // slab A: h1 -> o -> h2
  bf16* o_buf   = (bf16*)(ws);
  bf16* q_buf   = (bf16*)(ws + TC2);
  bf16* k_buf   = (bf16*)(ws + 2*TC2);
  bf16* v_buf   = (bf16*)(ws + 3*TC2);
  bf16* x2_buf  = (bf16*)(ws + TC2);           // slab B (q dead after attn)
  bf16* hidh    = (bf16*)(ws + 2*TC2);         // slabs C+D (k,v dead)
  float* x3     = (float*)(ws + TC2);          // slab B (x2 dead after LN2)
  char* sm = ws + 2*TC2;                       // smalls over dead hidh
  float* h3  = (float*)sm; sm += (size_t)T_*32*4;
  float* cq  = (float*)sm; sm += (size_t)B_*CHH_*32*14*4;
  float* ck  = (float*)sm; sm += (size_t)B_*CHH_*32*14*4;
  float* cv  = (float*)sm; sm += (size_t)B_*CHH_*32*14*4;
  float* co  = (float*)sm; sm += (size_t)B_*32*CN_*4;
  float* co2 = (float*)sm; sm += (size_t)B_*32*CN_*4;
  float* x4  = (float*)sm; sm += (size_t)T_*32*4;
  float* h4  = (float*)sm; sm += (size_t)T_*32*4;
  float* chid = (float*)sm;

  // 1. h1 = LN(x)
  ln768_kernel<true><<<T_, 256, 0, stream>>>(x, g1, b1, h_buf);
  // 2. qkv = h1 @ w_qkv^T, scattered to (B,H,N,64)
  gemm_bt<0><<<dim3(T_/BM, 2304/BN), 256, 0, stream>>>((const u16*)h_buf, w_qkv,
      nullptr, nullptr, nullptr, nullptr, q_buf, k_buf, v_buf, T_, 3*C_, C_, C_);
  // 3. attention -> o (slab A, h1 dead)
  attn_kernel<<<B_*H_, 256, 0, stream>>>((const u16*)q_buf, (const u16*)k_buf,
      (const u16*)v_buf, o_buf);
  // 4. x2 = x + o @ w_proj^T + b_proj  (slab B, q dead)
  gemm_bt<1><<<dim3(T_/BM, C_/BN), 256, 0, stream>>>((const u16*)o_buf, w_proj,
      b_proj, x, nullptr, x2_buf, nullptr, nullptr, nullptr, T_, C_, C_, C_);
  // 5. h2 = LN(x2) -> slab A (o dead)
  ln768_kernel<false><<<T_, 256, 0, stream>>>(x2_buf, g2, b2, h_buf);
  // 6-9. fc1+fc2 in two K-halves of 1536 (hidh in slabs C+D; x3 in slab B)
  for (int half=0; half<2; half++){
    gemm_bt<2><<<dim3(T_/BM, 1536/BN), 256, 0, stream>>>((const u16*)h_buf,
        w_fc1 + (size_t)half*1536*C_, b_fc1 + half*1536, nullptr,
        nullptr, hidh, nullptr, nullptr, nullptr, T_, 1536, C_, C_);
    if (half==0)
      gemm_bt<3><<<dim3(T_/BM, 1), 256, 0, stream>>>((const u16*)hidh,
          w_fc2, b_fc2, nullptr, x3, nullptr, nullptr, nullptr, nullptr,
          T_, OUT_, 1536, MH_);
    else
      gemm_bt<4><<<dim3(T_/BM, 1), 256, 0, stream>>>((const u16*)hidh,
          w_fc2 + 1536, nullptr, nullptr, x3, nullptr, nullptr, nullptr, nullptr,
          T_, OUT_, 1536, MH_);
  }
  // 10. h3 = LN(x3)
  ln32_kernel<<<(T_*32)/256, 256, 0, stream>>>(x3, g3, b3, h3);
  // 11. channel qkv
  cqkv_kernel<<<B_, 256, 0, stream>>>(h3, w_cqkv, cq, ck, cv);
  // 12. channel attention
  cattn_kernel<<<B_*CHH_, 64, 0, stream>>>(cq, ck, cv, co);
  // 13. channel proj
  cproj_kernel<<<B_, 256, 0, stream>>>(co, w_cproj, b_cproj, co2);
  // 14. x4 = x3 + concat([cls, co2^T])
  concat_add_kernel<<<(T_*32)/256, 256, 0, stream>>>(x3, h3, co2, x4);
  // 15. h4 = LN(x4)
  ln32_kernel<<<(T_*32)/256, 256, 0, stream>>>(x4, g4, b4, h4);
  // 16. chid = gelu(h4 @ w_cfc1^T + b_cfc1)
  cfc1_kernel<<<(T_*128)/256, 256, 0, stream>>>(h4, w_cfc1, b_cfc1, chid);
  // 17. out = x4 + chid @ w_cfc2^T + b_cfc2  (fp32 out)
  cfc2_kernel<<<(T_*32)/256, 256, 0, stream>>>(chid, w_cfc2, b_cfc2, x4, dout);
}

// Round 7
// 2267.284 us; speedup vs baseline: 2.6496x; 2.6496x over previous
//
#include <hip/hip_runtime.h>
#include <hip/hip_bf16.h>

typedef unsigned short u16;
typedef __hip_bfloat16 bf16;
typedef __attribute__((ext_vector_type(8))) short bf16x8;
typedef __attribute__((ext_vector_type(4))) float f32x4;

#define B_   128
#define N_   197
#define C_   768
#define H_   12
#define HD_  64
#define T_   (B_*N_)      // 25216 rows (394*64)
#define MH_  3072
#define OUT_ 32
#define CN_  196
#define CHH_ 14
#define NP_  208          // padded attention N (13*16)

__device__ __forceinline__ float bfu2f(u16 x){ union{unsigned u; float f;} v; v.u=((unsigned)x)<<16; return v.f; }
__device__ __forceinline__ bf16  f2bf(float f){ return __float2bfloat16(f); }
__device__ __forceinline__ u16   f2bfu(float f){ union{bf16 h; u16 u;} c; c.h=__float2bfloat16(f); return c.u; }
__device__ __forceinline__ float gelu_f(float x){ return 0.5f*x*(1.0f+erff(x*0.70710678118654752f)); }

__global__ __launch_bounds__(256) void write_code_kernel(float* out, int n, float code){
  int i = blockIdx.x*256 + threadIdx.x;
  if (i < n) out[i] = code;
}

// ---------------- LayerNorm over 768 (fp32 or bf16 in -> bf16 out) ----------------
template<bool F32IN>
__global__ __launch_bounds__(256) void ln768_kernel(const void* __restrict__ xv,
    const float* __restrict__ g, const float* __restrict__ b, bf16* __restrict__ out)
{
  int row = blockIdx.x;
  int tid = threadIdx.x;
  float v0, v1, v2;
  if (F32IN){
    const float* xr = (const float*)xv + (size_t)row*C_;
    v0 = xr[tid]; v1 = xr[tid+256]; v2 = xr[tid+512];
  } else {
    const u16* xr = (const u16*)xv + (size_t)row*C_;
    v0 = bfu2f(xr[tid]); v1 = bfu2f(xr[tid+256]); v2 = bfu2f(xr[tid+512]);
  }
  __shared__ float red[4];
  int lane = tid & 63, wave = tid >> 6;
  float s = v0+v1+v2;
  #pragma unroll
  for (int off=32; off>0; off>>=1) s += __shfl_xor(s, off);
  if (lane==0) red[wave]=s;
  __syncthreads();
  float mean = (red[0]+red[1]+red[2]+red[3]) * (1.0f/C_);
  float d0=v0-mean, d1=v1-mean, d2=v2-mean;
  float q = d0*d0+d1*d1+d2*d2;
  #pragma unroll
  for (int off=32; off>0; off>>=1) q += __shfl_xor(q, off);
  __syncthreads();
  if (lane==0) red[wave]=q;
  __syncthreads();
  float var = (red[0]+red[1]+red[2]+red[3]) * (1.0f/C_);
  float r = rsqrtf(var + 1e-5f);
  bf16* orow = out + (size_t)row*C_;
  orow[tid]     = f2bf(d0*r*g[tid]     + b[tid]);
  orow[tid+256] = f2bf(d1*r*g[tid+256] + b[tid+256]);
  orow[tid+512] = f2bf(d2*r*g[tid+512] + b[tid+512]);
}

// ---------------- LayerNorm over 32 (f32 in -> f32 out) ----------------
__global__ __launch_bounds__(256) void ln32_kernel(const float* __restrict__ x,
    const float* __restrict__ g, const float* __restrict__ b, float* __restrict__ out)
{
  int i = blockIdx.x*256 + threadIdx.x;
  int c = i & 31;
  float v = x[i];
  float s = v;
  #pragma unroll
  for (int off=16; off>0; off>>=1) s += __shfl_xor(s, off, 32);
  float mean = s * (1.0f/32);
  float d = v - mean;
  float q = d*d;
  #pragma unroll
  for (int off=16; off>0; off>>=1) q += __shfl_xor(q, off, 32);
  float r = rsqrtf(q*(1.0f/32) + 1e-5f);
  out[i] = d*r*g[c] + b[c];
}

// ================= MFMA GEMM: out[M,N] = A[M,K](bf16) @ W[N,K](f32->bf16)^T ====
// 64x64 tile, BK=32, 4 waves; wave w computes rows [w*16,w*16+16) x 64 cols.
// MODE 0: scatter q/k/v (B,H,N,64) bf16; MODE 1: +bias+resid -> bf16;
// MODE 2: gelu(+bias) -> bf16
template<int MODE>
__global__ __launch_bounds__(256) void gemm_mfma(
    const u16* __restrict__ A, const float* __restrict__ W,
    const float* __restrict__ bias, const float* __restrict__ resid,
    bf16* __restrict__ outb,
    bf16* __restrict__ q_out, bf16* __restrict__ k_out, bf16* __restrict__ v_out,
    int M, int Nn, int K, int wld)
{
  __shared__ __align__(16) u16 As[64][32];
  __shared__ __align__(16) u16 Bs[64][32];
  const int tid  = threadIdx.x;
  const int wave = tid >> 6, lane = tid & 63;
  const int quad = lane >> 4, l16 = lane & 15;
  const int m0 = blockIdx.x * 64;
  const int n0 = blockIdx.y * 64;
  // staging: thread t handles row t>>2, k-cols (t&3)*8 .. +7
  const int rs = tid >> 2;
  const int kc = (tid & 3) << 3;
  const u16*   arow = A + (size_t)(m0 + rs)*K  + kc;
  const float* wrow = W + (size_t)(n0 + rs)*wld + kc;

  f32x4 acc[4] = {};   // 4 n-subtiles of 16

  for (int k0 = 0; k0 < K; k0 += 32){
    *(uint4*)&As[rs][kc] = *(const uint4*)(arow + k0);       // 8 bf16 = 16B
    float4 w0 = *(const float4*)(wrow + k0);
    float4 w1 = *(const float4*)(wrow + k0 + 4);
    ushort4 b0; b0.x=f2bfu(w0.x); b0.y=f2bfu(w0.y); b0.z=f2bfu(w0.z); b0.w=f2bfu(w0.w);
    ushort4 b1; b1.x=f2bfu(w1.x); b1.y=f2bfu(w1.y); b1.z=f2bfu(w1.z); b1.w=f2bfu(w1.w);
    *(ushort4*)&Bs[rs][kc]   = b0;
    *(ushort4*)&Bs[rs][kc+4] = b1;
    __syncthreads();
    bf16x8 af = *(const bf16x8*)&As[wave*16 + l16][quad*8];
    #pragma unroll
    for (int nb=0; nb<4; nb++){
      bf16x8 bfr = *(const bf16x8*)&Bs[nb*16 + l16][quad*8];
      acc[nb] = __builtin_amdgcn_mfma_f32_16x16x32_bf16(af, bfr, acc[nb], 0, 0, 0);
    }
    __syncthreads();
  }

  // epilogue: C/D layout row = quad*4+r, col = l16 (within 16x16 subtile)
  #pragma unroll
  for (int nb=0; nb<4; nb++){
    #pragma unroll
    for (int r=0; r<4; r++){
      int m = m0 + wave*16 + quad*4 + r;
      int c = n0 + nb*16 + l16;
      float v = acc[nb][r];
      if (MODE==0){
        int bb = m / N_;
        int n  = m - bb*N_;
        int sec = c / C_;
        int rem = c - sec*C_;
        int hh  = rem >> 6;
        int d   = rem & 63;
        bf16* dst = (sec==0) ? q_out : (sec==1) ? k_out : v_out;
        dst[(((size_t)bb*H_ + hh)*N_ + n)*HD_ + d] = f2bf(v);
      } else if (MODE==1){
        size_t idx = (size_t)m*Nn + c;
        outb[idx] = f2bf(v + bias[c] + resid[idx]);
      } else {
        outb[(size_t)m*Nn + c] = f2bf(gelu_f(v + bias[c]));
      }
    }
  }
}

// ---------------- VALU GEMM (kept for fc2: small N) ----------------
// MODE 3: + bias -> f32 write ; MODE 4: accumulate -> f32 +=
#define BM 64
#define BN 64
#define BK 16
template<int MODE>
__global__ __launch_bounds__(256) void gemm_bt(
    const u16* __restrict__ A, const float* __restrict__ W,
    const float* __restrict__ bias,
    float* __restrict__ outf,
    int M, int Nn, int K, int wld)
{
  __shared__ __align__(16) float As[BK][BM];
  __shared__ __align__(16) float Ws[BK][BN];
  const int tid = threadIdx.x;
  const int m0 = blockIdx.x * BM;
  const int n0 = blockIdx.y * BN;
  const int tx = tid & 15;
  const int ty = tid >> 4;
  const int lr = tid >> 2;
  const int lc = (tid & 3) << 2;
  float acc[4][4] = {};
  const u16* ap = A + (size_t)(m0+lr)*K + lc;
  const bool wvalid = (n0 + lr) < Nn;
  const float* wp = W + (size_t)(n0+lr)*wld + lc;
  for (int k0=0; k0<K; k0+=BK){
    ushort4 av = *(const ushort4*)(ap + k0);
    As[lc+0][lr] = bfu2f(av.x);
    As[lc+1][lr] = bfu2f(av.y);
    As[lc+2][lr] = bfu2f(av.z);
    As[lc+3][lr] = bfu2f(av.w);
    float4 wv = make_float4(0.f,0.f,0.f,0.f);
    if (wvalid) wv = *(const float4*)(wp + k0);
    Ws[lc+0][lr] = wv.x;
    Ws[lc+1][lr] = wv.y;
    Ws[lc+2][lr] = wv.z;
    Ws[lc+3][lr] = wv.w;
    __syncthreads();
    #pragma unroll
    for (int kk=0; kk<BK; kk++){
      float4 a = *(const float4*)&As[kk][ty<<2];
      float4 w = *(const float4*)&Ws[kk][tx<<2];
      float av_[4] = {a.x,a.y,a.z,a.w};
      float wv_[4] = {w.x,w.y,w.z,w.w};
      #pragma unroll
      for (int i=0;i<4;i++)
        #pragma unroll
        for (int j=0;j<4;j++)
          acc[i][j] += av_[i]*wv_[j];
    }
    __syncthreads();
  }
  #pragma unroll
  for (int i=0;i<4;i++){
    int m = m0 + (ty<<2) + i;
    #pragma unroll
    for (int j=0;j<4;j++){
      int c = n0 + (tx<<2) + j;
      if (c >= Nn) continue;
      float v = acc[i][j];
      if (MODE==3)      outf[(size_t)m*Nn + c] = v + bias[c];
      else              outf[(size_t)m*Nn + c] += v;
    }
  }
}

// ---------------- Fused attention v2: one block per (b,h), 4 q-rows/wave-iter ---
__global__ __launch_bounds__(256) void attn_kernel(const u16* __restrict__ q,
    const u16* __restrict__ k, const u16* __restrict__ v, bf16* __restrict__ o)
{
  __shared__ __align__(16) u16 Ks[N_][66];        // row-major K, stride 66 (2-way=free)
  __shared__ __align__(16) u16 Vt[64][NP_+2];     // V transposed [d][j], stride 210
  __shared__ __align__(16) float qs[4][4][64];    // [wave][r][d]
  __shared__ __align__(16) float ps[4][4][NP_];   // [wave][r][j]
  int bh = blockIdx.x;
  int b  = bh / H_;
  int hh = bh - b*H_;
  int tid = threadIdx.x, wave = tid>>6, lane = tid&63;
  const u16* qb = q + (size_t)bh*N_*HD_;
  const u16* kb = k + (size_t)bh*N_*HD_;
  const u16* vb = v + (size_t)bh*N_*HD_;
  for (int idx=tid; idx<N_*HD_; idx+=256){
    int j = idx >> 6, d = idx & 63;
    Ks[j][d] = kb[idx];
    Vt[d][j] = vb[idx];
  }
  // zero pad Vt columns j in [197, 210)
  for (int idx=tid; idx<64*13; idx+=256){
    int d = idx/13, j = 197 + idx - (idx/13)*13;
    Vt[d][j] = 0;
  }
  __syncthreads();

  for (int g = wave; g < 50; g += 4){
    int r0 = g*4;
    #pragma unroll
    for (int r=0;r<4;r++){
      int qi = r0 + r;
      qs[wave][r][lane] = (qi < N_) ? bfu2f(qb[qi*HD_ + lane]) : 0.f;
    }
    float acc[4][4];    // [r][t]
    #pragma unroll
    for (int r=0;r<4;r++)
      #pragma unroll
      for (int t=0;t<4;t++) acc[r][t]=0.f;
    int jbase[4]; bool jok[4];
    #pragma unroll
    for (int t=0;t<4;t++){ jbase[t] = lane + (t<<6); jok[t] = jbase[t] < N_; }

    // ---- QK^T: dd-outer, 32 fma per (4 K-reads + 4 q-reads) ----
    for (int dd=0; dd<64; dd+=2){
      float2 qv[4];
      #pragma unroll
      for (int r=0;r<4;r++) qv[r] = *(const float2*)&qs[wave][r][dd];
      #pragma unroll
      for (int t=0;t<4;t++){
        if (!jok[t]) continue;
        unsigned pk = *(const unsigned*)&Ks[jbase[t]][dd];
        float k0f = bfu2f((u16)(pk & 0xffffu));
        float k1f = bfu2f((u16)(pk >> 16));
        #pragma unroll
        for (int r=0;r<4;r++)
          acc[r][t] += qv[r].x*k0f + qv[r].y*k1f;
      }
    }

    // ---- softmax per row ----
    #pragma unroll
    for (int r=0;r<4;r++){
      float mx = -1e30f;
      #pragma unroll
      for (int t=0;t<4;t++){
        acc[r][t] = jok[t] ? acc[r][t]*0.125f : -1e30f;
        mx = fmaxf(mx, acc[r][t]);
      }
      #pragma unroll
      for (int off=32; off>0; off>>=1) mx = fmaxf(mx, __shfl_xor(mx, off));
      float sum = 0.f;
      #pragma unroll
      for (int t=0;t<4;t++){
        float p = expf(acc[r][t] - mx);   // masked -> exp(-1e30) = 0
        acc[r][t] = p;
        sum += p;
      }
      #pragma unroll
      for (int off=32; off>0; off>>=1) sum += __shfl_xor(sum, off);
      float inv = 1.0f/sum;
      #pragma unroll
      for (int t=0;t<4;t++){
        int j = jbase[t];
        if (j < NP_) ps[wave][r][j] = acc[r][t]*inv;   // j in [197,208) -> 0
      }
    }

    // ---- P*V: packed-by-j V reads, b128 broadcast P reads ----
    float oacc[4] = {0.f,0.f,0.f,0.f};
    for (int jj=0; jj<NP_; jj+=4){
      ushort2 va = *(const ushort2*)&Vt[lane][jj];
      ushort2 vb2= *(const ushort2*)&Vt[lane][jj+2];
      float v0=bfu2f(va.x), v1=bfu2f(va.y), v2=bfu2f(vb2.x), v3=bfu2f(vb2.y);
      #pragma unroll
      for (int r=0;r<4;r++){
        float4 pp = *(const float4*)&ps[wave][r][jj];
        oacc[r] += pp.x*v0 + pp.y*v1 + pp.z*v2 + pp.w*v3;
      }
    }
    #pragma unroll
    for (int r=0;r<4;r++){
      int qi = r0 + r;
      if (qi < N_)
        o[((size_t)b*N_ + qi)*C_ + hh*HD_ + lane] = f2bf(oacc[r]);
    }
  }
}

// ---------------- channel qkv: per b, (32x196) @ (588x196)^T, scatter ----------
__global__ __launch_bounds__(256) void cqkv_kernel(const float* __restrict__ h3,
    const float* __restrict__ w, float* __restrict__ cq, float* __restrict__ ck,
    float* __restrict__ cv)
{
  __shared__ __align__(16) float ts[32*201];
  int b = blockIdx.x, tid = threadIdx.x;
  for (int idx=tid; idx<CN_*32; idx+=256){
    int n = idx >> 5, o = idx & 31;
    ts[o*201+n] = h3[((size_t)b*N_ + 1 + n)*32 + o];
  }
  __syncthreads();
  for (int idx=tid; idx<32*588; idx+=256){
    int o = idx / 588, j = idx - o*588;
    const float* wr = w + (size_t)j*CN_;
    float acc = 0.f;
    for (int kk=0; kk<CN_; kk++) acc += ts[o*201+kk] * wr[kk];
    int sec = j / CN_;
    int rem = j - sec*CN_;
    int hh  = rem / 14;
    int d   = rem - hh*14;
    float* dst = (sec==0) ? cq : (sec==1) ? ck : cv;
    dst[(((size_t)b*CHH_ + hh)*32 + o)*14 + d] = acc;
  }
}

// ---------------- channel attention: one wave per (b,head) ----------------
__global__ __launch_bounds__(64) void cattn_kernel(const float* __restrict__ cq,
    const float* __restrict__ ck, const float* __restrict__ cv, float* __restrict__ co)
{
  __shared__ __align__(16) float qs[32*15], ks_[32*15], vs[32*15], ps[32*34];
  int bh = blockIdx.x;
  int b  = bh / CHH_;
  int hh = bh - b*CHH_;
  int lane = threadIdx.x;
  const float* qb = cq + (size_t)bh*448;
  const float* kb = ck + (size_t)bh*448;
  const float* vb = cv + (size_t)bh*448;
  for (int idx=lane; idx<448; idx+=64){
    int o = idx/14, d = idx - o*14;
    qs[o*15+d] = qb[idx]; ks_[o*15+d] = kb[idx]; vs[o*15+d] = vb[idx];
  }
  __syncthreads();
  int o = lane & 31, half = lane >> 5;
  const float scale = 0.2672612419124244f;
  float sc[16]; float mx = -1e30f;
  #pragma unroll
  for (int jj=0; jj<16; jj++){
    int j = half*16 + jj;
    float a = 0.f;
    #pragma unroll
    for (int d=0; d<14; d++) a += qs[o*15+d]*ks_[j*15+d];
    sc[jj] = a*scale;
    mx = fmaxf(mx, sc[jj]);
  }
  mx = fmaxf(mx, __shfl_xor(mx, 32));
  float sum = 0.f;
  #pragma unroll
  for (int jj=0; jj<16; jj++){ sc[jj] = expf(sc[jj]-mx); sum += sc[jj]; }
  sum += __shfl_xor(sum, 32);
  float inv = 1.0f/sum;
  #pragma unroll
  for (int jj=0; jj<16; jj++) ps[o*34 + half*16 + jj] = sc[jj]*inv;
  __syncthreads();
  #pragma unroll
  for (int dd=0; dd<7; dd++){
    int d = half*7 + dd;
    float acc = 0.f;
    #pragma unroll
    for (int j=0; j<32; j++) acc += ps[o*34+j]*vs[j*15+d];
    co[((size_t)b*32 + o)*CN_ + hh*14 + d] = acc;
  }
}

// ---------------- channel proj: per b, (32x196) @ (196x196)^T + bias ----------
__global__ __launch_bounds__(256) void cproj_kernel(const float* __restrict__ co,
    const float* __restrict__ w, const float* __restrict__ bias, float* __restrict__ co2)
{
  __shared__ __align__(16) float cs[32*201];
  int b = blockIdx.x, tid = threadIdx.x;
  for (int idx=tid; idx<32*CN_; idx+=256){
    int o = idx / CN_, n = idx - o*CN_;
    cs[o*201+n] = co[(size_t)b*32*CN_ + idx];
  }
  __syncthreads();
  for (int idx=tid; idx<32*CN_; idx+=256){
    int o = idx / CN_, j = idx - o*CN_;
    const float* wr = w + (size_t)j*CN_;
    float acc = bias[j];
    for (int kk=0; kk<CN_; kk++) acc += cs[o*201+kk]*wr[kk];
    co2[(size_t)b*32*CN_ + o*CN_ + j] = acc;
  }
}

// ---------------- x4 = x3 + concat([cls(h3), co2^T]) ----------------
__global__ __launch_bounds__(256) void concat_add_kernel(const float* __restrict__ x3,
    const float* __restrict__ h3, const float* __restrict__ co2, float* __restrict__ x4)
{
  int i = blockIdx.x*256 + threadIdx.x;
  int c = i & 31;
  int row = i >> 5;
  int b = row / N_;
  int r = row - b*N_;
  float add = (r==0) ? h3[i] : co2[((size_t)b*32 + c)*CN_ + (r-1)];
  x4[i] = x3[i] + add;
}

// ---------------- cfc1: gelu(h4 @ w^T + b), K=32 -> 128 ----------------
__global__ __launch_bounds__(256) void cfc1_kernel(const float* __restrict__ h4,
    const float* __restrict__ w, const float* __restrict__ bias, float* __restrict__ chid)
{
  int idx = blockIdx.x*256 + threadIdx.x;
  int m = idx >> 7, j = idx & 127;
  const float* hr = h4 + (size_t)m*32;
  const float* wr = w + (size_t)j*32;
  float acc = bias[j];
  #pragma unroll
  for (int kk=0; kk<32; kk++) acc += hr[kk]*wr[kk];
  chid[idx] = gelu_f(acc);
}

// ---------------- cfc2: out = x4 + chid @ w^T + b, K=128 -> 32, FP32 out -------
__global__ __launch_bounds__(256) void cfc2_kernel(const float* __restrict__ chid,
    const float* __restrict__ w, const float* __restrict__ bias,
    const float* __restrict__ x4, float* __restrict__ out)
{
  int idx = blockIdx.x*256 + threadIdx.x;
  int m = idx >> 5, j = idx & 31;
  const float* cr = chid + (size_t)m*128;
  const float* wr = w + (size_t)j*128;
  float acc = bias[j];
  #pragma unroll
  for (int kk=0; kk<128; kk++) acc += cr[kk]*wr[kk];
  out[idx] = x4[idx] + acc;
}

extern "C" void kernel_launch(void* const* d_in, const int* in_sizes, int n_in,
                              void* d_out, int out_size, void* d_ws, size_t ws_size,
                              hipStream_t stream)
{
  const int NIN = 23;
  static const int dsz[NIN] = {19365888,768,768,1769472,589824,768,768,768,2359296,
                               3072,98304,32,32,32,115248,38416,196,32,32,4096,128,4096,32};
  static const int a2d[NIN] = {2,7,13,18,20,22,16,9,11,5,1,6,12,17,19,21,15,14,8,10,4,3,0};

  float* dout = (float*)d_out;
  int ogrid = (out_size + 255)/256;

  const float* in[NIN];
  bool dict_ok = (n_in == NIN);
  if (dict_ok) for (int i=0;i<NIN;i++) if (in_sizes[i] != dsz[i]) { dict_ok=false; break; }
  if (dict_ok){
    for (int i=0;i<NIN;i++) in[i] = (const float*)d_in[i];
  } else {
    bool alpha_ok = (n_in == NIN);
    if (alpha_ok) for (int i=0;i<NIN;i++) if (in_sizes[i] != dsz[a2d[i]]) { alpha_ok=false; break; }
    if (alpha_ok){
      for (int i=0;i<NIN;i++) in[a2d[i]] = (const float*)d_in[i];
    } else {
      write_code_kernel<<<ogrid, 256, 0, stream>>>(dout, out_size, 5000.f + (float)n_in);
      return;
    }
  }

  const float* x      = in[0];
  const float* g1     = in[1];
  const float* b1     = in[2];
  const float* w_qkv  = in[3];
  const float* w_proj = in[4];
  const float* b_proj = in[5];
  const float* g2     = in[6];
  const float* b2     = in[7];
  const float* w_fc1  = in[8];
  const float* b_fc1  = in[9];
  const float* w_fc2  = in[10];
  const float* b_fc2  = in[11];
  const float* g3     = in[12];
  const float* b3     = in[13];
  const float* w_cqkv = in[14];
  const float* w_cproj= in[15];
  const float* b_cproj= in[16];
  const float* g4     = in[17];
  const float* b4     = in[18];
  const float* w_cfc1 = in[19];
  const float* b_cfc1 = in[20];
  const float* w_cfc2 = in[21];
  const float* b_cfc2 = in[22];

  char* ws = (char*)d_ws;
  const size_t TC2 = (size_t)T_*C_*2;          // 38,731,776 B
  const size_t NEED = 4*TC2 + 4096;
  if (ws_size < NEED){
    write_code_kernel<<<ogrid, 256, 0, stream>>>(dout, out_size,
        7000.f + (float)(ws_size >> 20));
    return;
  }

  // -------- workspace layout, peak 4*TC2 ~= 148 MB (bf16 intermediates) --------
  bf16* h_buf   = (bf16*)(ws);                 // slab A: h1 -> o -> h2
  bf16* o_buf   = (bf16*)(ws);
  bf16* q_buf   = (bf16*)(ws + TC2);
  bf16* k_buf   = (bf16*)(ws + 2*TC2);
  bf16* v_buf   = (bf16*)(ws + 3*TC2);
  bf16* x2_buf  = (bf16*)(ws + TC2);           // slab B (q dead after attn)
  bf16* hidh    = (bf16*)(ws + 2*TC2);         // slabs C+D (k,v dead)
  float* x3     = (float*)(ws + TC2);          // slab B (x2 dead after LN2)
  char* sm = ws + 2*TC2;                       // smalls over dead hidh
  float* h3  = (float*)sm; sm += (size_t)T_*32*4;
  float* cq  = (float*)sm; sm += (size_t)B_*CHH_*32*14*4;
  float* ck  = (float*)sm; sm += (size_t)B_*CHH_*32*14*4;
  float* cv  = (float*)sm; sm += (size_t)B_*CHH_*32*14*4;
  float* co  = (float*)sm; sm += (size_t)B_*32*CN_*4;
  float* co2 = (float*)sm; sm += (size_t)B_*32*CN_*4;
  float* x4  = (float*)sm; sm += (size_t)T_*32*4;
  float* h4  = (float*)sm; sm += (size_t)T_*32*4;
  float* chid = (float*)sm;

  // 1. h1 = LN(x)
  ln768_kernel<true><<<T_, 256, 0, stream>>>(x, g1, b1, h_buf);
  // 2. qkv = h1 @ w_qkv^T (MFMA), scattered to (B,H,N,64)
  gemm_mfma<0><<<dim3(T_/64, 2304/64), 256, 0, stream>>>((const u16*)h_buf, w_qkv,
      nullptr, nullptr, nullptr, q_buf, k_buf, v_buf, T_, 3*C_, C_, C_);
  // 3. attention -> o (slab A, h1 dead)
  attn_kernel<<<B_*H_, 256, 0, stream>>>((const u16*)q_buf, (const u16*)k_buf,
      (const u16*)v_buf, o_buf);
  // 4. x2 = x + o @ w_proj^T + b_proj (MFMA; slab B, q dead)
  gemm_mfma<1><<<dim3(T_/64, C_/64), 256, 0, stream>>>((const u16*)o_buf, w_proj,
      b_proj, x, x2_buf, nullptr, nullptr, nullptr, T_, C_, C_, C_);
  // 5. h2 = LN(x2) -> slab A (o dead)
  ln768_kernel<false><<<T_, 256, 0, stream>>>(x2_buf, g2, b2, h_buf);
  // 6-9. fc1 (MFMA) + fc2 (VALU) in two K-halves of 1536
  for (int half=0; half<2; half++){
    gemm_mfma<2><<<dim3(T_/64, 1536/64), 256, 0, stream>>>((const u16*)h_buf,
        w_fc1 + (size_t)half*1536*C_, b_fc1 + half*1536, nullptr,
        hidh, nullptr, nullptr, nullptr, T_, 1536, C_, C_);
    if (half==0)
      gemm_bt<3><<<dim3(T_/BM, 1), 256, 0, stream>>>((const u16*)hidh,
          w_fc2, b_fc2, x3, T_, OUT_, 1536, MH_);
    else
      gemm_bt<4><<<dim3(T_/BM, 1), 256, 0, stream>>>((const u16*)hidh,
          w_fc2 + 1536, nullptr, x3, T_, OUT_, 1536, MH_);
  }
  // 10. h3 = LN(x3)
  ln32_kernel<<<(T_*32)/256, 256, 0, stream>>>(x3, g3, b3, h3);
  // 11. channel qkv
  cqkv_kernel<<<B_, 256, 0, stream>>>(h3, w_cqkv, cq, ck, cv);
  // 12. channel attention
  cattn_kernel<<<B_*CHH_, 64, 0, stream>>>(cq, ck, cv, co);
  // 13. channel proj
  cproj_kernel<<<B_, 256, 0, stream>>>(co, w_cproj, b_cproj, co2);
  // 14. x4 = x3 + concat([cls, co2^T])
  concat_add_kernel<<<(T_*32)/256, 256, 0, stream>>>(x3, h3, co2, x4);
  // 15. h4 = LN(x4)
  ln32_kernel<<<(T_*32)/256, 256, 0, stream>>>(x4, g4, b4, h4);
  // 16. chid = gelu(h4 @ w_cfc1^T + b_cfc1)
  cfc1_kernel<<<(T_*128)/256, 256, 0, stream>>>(h4, w_cfc1, b_cfc1, chid);
  // 17. out = x4 + chid @ w_cfc2^T + b_cfc2  (fp32 out)
  cfc2_kernel<<<(T_*32)/256, 256, 0, stream>>>(chid, w_cfc2, b_cfc2, x4, dout);
}

// Round 8
// 1341.936 us; speedup vs baseline: 4.4767x; 1.6896x over previous
//
#include <hip/hip_runtime.h>
#include <hip/hip_bf16.h>

typedef unsigned short u16;
typedef __hip_bfloat16 bf16;
typedef __attribute__((ext_vector_type(8))) short bf16x8;
typedef __attribute__((ext_vector_type(4))) float f32x4;

#define B_   128
#define N_   197
#define C_   768
#define H_   12
#define HD_  64
#define T_   (B_*N_)      // 25216 rows (394*64)
#define MH_  3072
#define OUT_ 32
#define CN_  196
#define CHH_ 14
#define KP_  224          // channel K padded to 7*32
#define CSZ_ (B_*CHH_*32*14)   // per-tensor channel qkv size

__device__ __forceinline__ float bfu2f(u16 x){ union{unsigned u; float f;} v; v.u=((unsigned)x)<<16; return v.f; }
__device__ __forceinline__ bf16  f2bf(float f){ return __float2bfloat16(f); }
__device__ __forceinline__ u16   f2bfu(float f){ union{bf16 h; u16 u;} c; c.h=__float2bfloat16(f); return c.u; }
__device__ __forceinline__ float gelu_f(float x){ return 0.5f*x*(1.0f+erff(x*0.70710678118654752f)); }

__global__ __launch_bounds__(256) void write_code_kernel(float* out, int n, float code){
  int i = blockIdx.x*256 + threadIdx.x;
  if (i < n) out[i] = code;
}

// ---------------- LayerNorm over 768 ----------------
template<bool F32IN>
__global__ __launch_bounds__(256) void ln768_kernel(const void* __restrict__ xv,
    const float* __restrict__ g, const float* __restrict__ b, bf16* __restrict__ out)
{
  int row = blockIdx.x;
  int tid = threadIdx.x;
  float v0, v1, v2;
  if (F32IN){
    const float* xr = (const float*)xv + (size_t)row*C_;
    v0 = xr[tid]; v1 = xr[tid+256]; v2 = xr[tid+512];
  } else {
    const u16* xr = (const u16*)xv + (size_t)row*C_;
    v0 = bfu2f(xr[tid]); v1 = bfu2f(xr[tid+256]); v2 = bfu2f(xr[tid+512]);
  }
  __shared__ float red[4];
  int lane = tid & 63, wave = tid >> 6;
  float s = v0+v1+v2;
  #pragma unroll
  for (int off=32; off>0; off>>=1) s += __shfl_xor(s, off);
  if (lane==0) red[wave]=s;
  __syncthreads();
  float mean = (red[0]+red[1]+red[2]+red[3]) * (1.0f/C_);
  float d0=v0-mean, d1=v1-mean, d2=v2-mean;
  float q = d0*d0+d1*d1+d2*d2;
  #pragma unroll
  for (int off=32; off>0; off>>=1) q += __shfl_xor(q, off);
  __syncthreads();
  if (lane==0) red[wave]=q;
  __syncthreads();
  float var = (red[0]+red[1]+red[2]+red[3]) * (1.0f/C_);
  float r = rsqrtf(var + 1e-5f);
  bf16* orow = out + (size_t)row*C_;
  orow[tid]     = f2bf(d0*r*g[tid]     + b[tid]);
  orow[tid+256] = f2bf(d1*r*g[tid+256] + b[tid+256]);
  orow[tid+512] = f2bf(d2*r*g[tid+512] + b[tid+512]);
}

// ---------------- LayerNorm over 32 ----------------
__global__ __launch_bounds__(256) void ln32_kernel(const float* __restrict__ x,
    const float* __restrict__ g, const float* __restrict__ b, float* __restrict__ out)
{
  int i = blockIdx.x*256 + threadIdx.x;
  int c = i & 31;
  float v = x[i];
  float s = v;
  #pragma unroll
  for (int off=16; off>0; off>>=1) s += __shfl_xor(s, off, 32);
  float mean = s * (1.0f/32);
  float d = v - mean;
  float q = d*d;
  #pragma unroll
  for (int off=16; off>0; off>>=1) q += __shfl_xor(q, off, 32);
  float r = rsqrtf(q*(1.0f/32) + 1e-5f);
  out[i] = d*r*g[c] + b[c];
}

// ================= MFMA GEMM: out[M,N] = A[M,K](bf16) @ W[N,K]^T ====
// W fp32 (converted in staging) when WB16=false, bf16 pre-packed when WB16=true.
// MODE 0: scatter q/k/v bf16 | 1: +bias+resid->bf16 | 2: gelu+bias->bf16
// MODE 3: +bias->f32 (c<Nn) | 4: f32 += | 5: channel-qkv scatter f32
template<int MODE, bool WB16>
__global__ __launch_bounds__(256) void gemm_mfma(
    const u16* __restrict__ A, const void* __restrict__ Wsrc,
    const float* __restrict__ bias, const float* __restrict__ resid,
    bf16* __restrict__ outb, float* __restrict__ outf,
    bf16* __restrict__ q_out, bf16* __restrict__ k_out, bf16* __restrict__ v_out,
    int M, int Nn, int K, int wld)
{
  __shared__ __align__(16) u16 As[64][32];
  __shared__ __align__(16) u16 Bs[64][32];
  const int tid  = threadIdx.x;
  const int wave = tid >> 6, lane = tid & 63;
  const int quad = lane >> 4, l16 = lane & 15;
  const int m0 = blockIdx.x * 64;
  const int n0 = blockIdx.y * 64;
  const int rs = tid >> 2;
  const int kc = (tid & 3) << 3;
  const u16* arow = A + (size_t)(m0 + rs)*K + kc;
  const bool wvalid = (n0 + rs) < Nn;

  f32x4 acc[4] = {};

  for (int k0 = 0; k0 < K; k0 += 32){
    *(uint4*)&As[rs][kc] = *(const uint4*)(arow + k0);
    if (WB16){
      const u16* wrow = (const u16*)Wsrc + (size_t)(n0 + rs)*wld + kc;
      uint4 wv = make_uint4(0u,0u,0u,0u);
      if (wvalid) wv = *(const uint4*)(wrow + k0);
      *(uint4*)&Bs[rs][kc] = wv;
    } else {
      const float* wrow = (const float*)Wsrc + (size_t)(n0 + rs)*wld + kc;
      float4 w0 = make_float4(0.f,0.f,0.f,0.f), w1 = w0;
      if (wvalid){ w0 = *(const float4*)(wrow + k0); w1 = *(const float4*)(wrow + k0 + 4); }
      ushort4 b0; b0.x=f2bfu(w0.x); b0.y=f2bfu(w0.y); b0.z=f2bfu(w0.z); b0.w=f2bfu(w0.w);
      ushort4 b1; b1.x=f2bfu(w1.x); b1.y=f2bfu(w1.y); b1.z=f2bfu(w1.z); b1.w=f2bfu(w1.w);
      *(ushort4*)&Bs[rs][kc]   = b0;
      *(ushort4*)&Bs[rs][kc+4] = b1;
    }
    __syncthreads();
    bf16x8 af = *(const bf16x8*)&As[wave*16 + l16][quad*8];
    #pragma unroll
    for (int nb=0; nb<4; nb++){
      bf16x8 bfr = *(const bf16x8*)&Bs[nb*16 + l16][quad*8];
      acc[nb] = __builtin_amdgcn_mfma_f32_16x16x32_bf16(af, bfr, acc[nb], 0, 0, 0);
    }
    __syncthreads();
  }

  #pragma unroll
  for (int nb=0; nb<4; nb++){
    #pragma unroll
    for (int r=0; r<4; r++){
      int m = m0 + wave*16 + quad*4 + r;
      int c = n0 + nb*16 + l16;
      float v = acc[nb][r];
      if (MODE==0){
        int bb = m / N_;
        int n  = m - bb*N_;
        int sec = c / C_;
        int rem = c - sec*C_;
        int hh  = rem >> 6;
        int d   = rem & 63;
        bf16* dst = (sec==0) ? q_out : (sec==1) ? k_out : v_out;
        dst[(((size_t)bb*H_ + hh)*N_ + n)*HD_ + d] = f2bf(v);
      } else if (MODE==1){
        size_t idx = (size_t)m*Nn + c;
        outb[idx] = f2bf(v + bias[c] + resid[idx]);
      } else if (MODE==2){
        outb[(size_t)m*Nn + c] = f2bf(gelu_f(v + bias[c]));
      } else if (MODE==3){
        if (c < Nn) outf[(size_t)m*Nn + c] = v + bias[c];
      } else if (MODE==4){
        if (c < Nn) outf[(size_t)m*Nn + c] += v;
      } else { // MODE 5: channel qkv scatter
        if (c < Nn){
          int bb = m >> 5, oo = m & 31;
          int sec = c / CN_;
          int rem = c - sec*CN_;
          int hh  = rem / 14;
          int d   = rem - hh*14;
          outf[(size_t)sec*CSZ_ + (((size_t)bb*CHH_ + hh)*32 + oo)*14 + d] = v;
        }
      }
    }
  }
}

// ---------------- MFMA attention: one block per (b,h), strip = 16 q-rows -------
__global__ __launch_bounds__(256) void attn_kernel(const u16* __restrict__ q,
    const u16* __restrict__ k, const u16* __restrict__ v, bf16* __restrict__ o)
{
  __shared__ __align__(16) u16 Vt[64][232];      // V^T [d][j], stride 232 (2-way max)
  __shared__ __align__(16) u16 Ps[4][16][232];   // per-wave P strip
  int bh = blockIdx.x, b = bh / H_, hh = bh - b*H_;
  int tid = threadIdx.x, wave = tid >> 6, lane = tid & 63;
  int quad = lane >> 4, l16 = lane & 15;
  const u16* qb = q + (size_t)bh*N_*HD_;
  const u16* kb = k + (size_t)bh*N_*HD_;
  const u16* vb = v + (size_t)bh*N_*HD_;
  for (int idx = tid; idx < N_*HD_; idx += 256){
    int j = idx >> 6, d = idx & 63;
    Vt[d][j] = vb[idx];
  }
  for (int idx = tid; idx < 64*(232-N_); idx += 256){
    int d = idx / (232-N_), j = N_ + (idx - d*(232-N_));
    Vt[d][j] = 0;
  }
  for (int idx = tid; idx < 4*16*232; idx += 256)
    ((u16*)Ps)[idx] = 0;
  __syncthreads();

  for (int g = wave; g < 13; g += 4){
    int r0 = g*16;
    int qrow = r0 + l16;
    int qr = (qrow < N_) ? qrow : 0;
    bf16x8 aq0 = *(const bf16x8*)(qb + (size_t)qr*HD_ + quad*8);
    bf16x8 aq1 = *(const bf16x8*)(qb + (size_t)qr*HD_ + 32 + quad*8);
    f32x4 s[13];
    #pragma unroll
    for (int nb = 0; nb < 13; nb++){
      int krow = nb*16 + l16;
      int kr = (krow < N_) ? krow : 0;
      bf16x8 bk0 = *(const bf16x8*)(kb + (size_t)kr*HD_ + quad*8);
      bf16x8 bk1 = *(const bf16x8*)(kb + (size_t)kr*HD_ + 32 + quad*8);
      f32x4 t = {};
      t = __builtin_amdgcn_mfma_f32_16x16x32_bf16(aq0, bk0, t, 0, 0, 0);
      t = __builtin_amdgcn_mfma_f32_16x16x32_bf16(aq1, bk1, t, 0, 0, 0);
      s[nb] = t;
    }
    // scale + mask (C/D: row = quad*4+r, col = nb*16+l16)
    #pragma unroll
    for (int nb = 0; nb < 13; nb++){
      bool colok = (nb*16 + l16) < N_;
      #pragma unroll
      for (int r = 0; r < 4; r++)
        s[nb][r] = colok ? s[nb][r]*0.125f : -1e30f;
    }
    // softmax per row: reduce across the 16 lanes of the quad
    #pragma unroll
    for (int r = 0; r < 4; r++){
      float m = s[0][r];
      #pragma unroll
      for (int nb = 1; nb < 13; nb++) m = fmaxf(m, s[nb][r]);
      m = fmaxf(m, __shfl_xor(m, 1));
      m = fmaxf(m, __shfl_xor(m, 2));
      m = fmaxf(m, __shfl_xor(m, 4));
      m = fmaxf(m, __shfl_xor(m, 8));
      float su = 0.f;
      #pragma unroll
      for (int nb = 0; nb < 13; nb++){
        float p = expf(s[nb][r] - m);
        s[nb][r] = p; su += p;
      }
      su += __shfl_xor(su, 1);
      su += __shfl_xor(su, 2);
      su += __shfl_xor(su, 4);
      su += __shfl_xor(su, 8);
      float inv = 1.0f/su;
      #pragma unroll
      for (int nb = 0; nb < 13; nb++) s[nb][r] *= inv;
    }
    // P -> LDS (bf16), A-layout round-trip
    #pragma unroll
    for (int nb = 0; nb < 13; nb++)
      #pragma unroll
      for (int r = 0; r < 4; r++)
        Ps[wave][quad*4 + r][nb*16 + l16] = f2bfu(s[nb][r]);
    __threadfence_block();   // order wave's ds_writes before ds_reads
    // O strip = P @ V  (A = P[m=qrow][k=j], B = Vt[d][j])
    f32x4 oa[4] = {};
    #pragma unroll
    for (int ks = 0; ks < 7; ks++){
      bf16x8 ap = *(const bf16x8*)&Ps[wave][l16][ks*32 + quad*8];
      #pragma unroll
      for (int nd = 0; nd < 4; nd++){
        bf16x8 bv = *(const bf16x8*)&Vt[nd*16 + l16][ks*32 + quad*8];
        oa[nd] = __builtin_amdgcn_mfma_f32_16x16x32_bf16(ap, bv, oa[nd], 0, 0, 0);
      }
    }
    #pragma unroll
    for (int nd = 0; nd < 4; nd++)
      #pragma unroll
      for (int r = 0; r < 4; r++){
        int qi = r0 + quad*4 + r;
        if (qi < N_)
          o[((size_t)b*N_ + qi)*C_ + hh*HD_ + nd*16 + l16] = f2bf(oa[nd][r]);
      }
    __threadfence_block();   // order PV reads before next strip's P writes
  }
}

// ---------------- channel packs ----------------
__global__ __launch_bounds__(256) void pack_tall_kernel(const float* __restrict__ h3,
    u16* __restrict__ tall)
{
  int idx = blockIdx.x*256 + threadIdx.x;   // 4096*KP_
  if (idx >= 4096*KP_) return;
  int row = idx / KP_, kk = idx - row*KP_;
  int b = row >> 5, oo = row & 31;
  float v = (kk < CN_) ? h3[((size_t)b*N_ + 1 + kk)*32 + oo] : 0.f;
  tall[idx] = f2bfu(v);
}

__global__ __launch_bounds__(256) void pack_w_kernel(const float* __restrict__ w,
    u16* __restrict__ dst, int rows, int kreal)
{
  int idx = blockIdx.x*256 + threadIdx.x;
  if (idx >= rows*KP_) return;
  int r = idx / KP_, kk = idx - r*KP_;
  dst[idx] = (kk < kreal) ? f2bfu(w[(size_t)r*kreal + kk]) : (u16)0;
}

__global__ __launch_bounds__(256) void pack_co_kernel(const float* __restrict__ co,
    u16* __restrict__ dst)
{
  int idx = blockIdx.x*256 + threadIdx.x;   // 4096*KP_
  if (idx >= 4096*KP_) return;
  int row = idx / KP_, kk = idx - row*KP_;
  dst[idx] = (kk < CN_) ? f2bfu(co[(size_t)row*CN_ + kk]) : (u16)0;
}

// ---------------- channel attention: one wave per (b,head) ----------------
__global__ __launch_bounds__(64) void cattn_kernel(const float* __restrict__ cq,
    const float* __restrict__ ck, const float* __restrict__ cv, float* __restrict__ co)
{
  __shared__ __align__(16) float qs[32*15], ks_[32*15], vs[32*15], ps[32*34];
  int bh = blockIdx.x;
  int b  = bh / CHH_;
  int hh = bh - b*CHH_;
  int lane = threadIdx.x;
  const float* qb = cq + (size_t)bh*448;
  const float* kb = ck + (size_t)bh*448;
  const float* vb = cv + (size_t)bh*448;
  for (int idx=lane; idx<448; idx+=64){
    int o = idx/14, d = idx - o*14;
    qs[o*15+d] = qb[idx]; ks_[o*15+d] = kb[idx]; vs[o*15+d] = vb[idx];
  }
  __syncthreads();
  int o = lane & 31, half = lane >> 5;
  const float scale = 0.2672612419124244f;
  float sc[16]; float mx = -1e30f;
  #pragma unroll
  for (int jj=0; jj<16; jj++){
    int j = half*16 + jj;
    float a = 0.f;
    #pragma unroll
    for (int d=0; d<14; d++) a += qs[o*15+d]*ks_[j*15+d];
    sc[jj] = a*scale;
    mx = fmaxf(mx, sc[jj]);
  }
  mx = fmaxf(mx, __shfl_xor(mx, 32));
  float sum = 0.f;
  #pragma unroll
  for (int jj=0; jj<16; jj++){ sc[jj] = expf(sc[jj]-mx); sum += sc[jj]; }
  sum += __shfl_xor(sum, 32);
  float inv = 1.0f/sum;
  #pragma unroll
  for (int jj=0; jj<16; jj++) ps[o*34 + half*16 + jj] = sc[jj]*inv;
  __syncthreads();
  #pragma unroll
  for (int dd=0; dd<7; dd++){
    int d = half*7 + dd;
    float acc = 0.f;
    #pragma unroll
    for (int j=0; j<32; j++) acc += ps[o*34+j]*vs[j*15+d];
    co[((size_t)b*32 + o)*CN_ + hh*14 + d] = acc;
  }
}

// ---------------- x4 = x3 + concat([cls(h3), co2^T]) ----------------
__global__ __launch_bounds__(256) void concat_add_kernel(const float* __restrict__ x3,
    const float* __restrict__ h3, const float* __restrict__ co2, float* __restrict__ x4)
{
  int i = blockIdx.x*256 + threadIdx.x;
  int c = i & 31;
  int row = i >> 5;
  int b = row / N_;
  int r = row - b*N_;
  float add = (r==0) ? h3[i] : co2[((size_t)b*32 + c)*CN_ + (r-1)];
  x4[i] = x3[i] + add;
}

// ---------------- cfc1: gelu(h4 @ w^T + b), K=32 -> 128 ----------------
__global__ __launch_bounds__(256) void cfc1_kernel(const float* __restrict__ h4,
    const float* __restrict__ w, const float* __restrict__ bias, float* __restrict__ chid)
{
  int idx = blockIdx.x*256 + threadIdx.x;
  int m = idx >> 7, j = idx & 127;
  const float* hr = h4 + (size_t)m*32;
  const float* wr = w + (size_t)j*32;
  float acc = bias[j];
  #pragma unroll
  for (int kk=0; kk<32; kk++) acc += hr[kk]*wr[kk];
  chid[idx] = gelu_f(acc);
}

// ---------------- cfc2: out = x4 + chid @ w^T + b, FP32 out ----------------
__global__ __launch_bounds__(256) void cfc2_kernel(const float* __restrict__ chid,
    const float* __restrict__ w, const float* __restrict__ bias,
    const float* __restrict__ x4, float* __restrict__ out)
{
  int idx = blockIdx.x*256 + threadIdx.x;
  int m = idx >> 5, j = idx & 31;
  const float* cr = chid + (size_t)m*128;
  const float* wr = w + (size_t)j*128;
  float acc = bias[j];
  #pragma unroll
  for (int kk=0; kk<128; kk++) acc += cr[kk]*wr[kk];
  out[idx] = x4[idx] + acc;
}

extern "C" void kernel_launch(void* const* d_in, const int* in_sizes, int n_in,
                              void* d_out, int out_size, void* d_ws, size_t ws_size,
                              hipStream_t stream)
{
  const int NIN = 23;
  static const int dsz[NIN] = {19365888,768,768,1769472,589824,768,768,768,2359296,
                               3072,98304,32,32,32,115248,38416,196,32,32,4096,128,4096,32};
  static const int a2d[NIN] = {2,7,13,18,20,22,16,9,11,5,1,6,12,17,19,21,15,14,8,10,4,3,0};

  float* dout = (float*)d_out;
  int ogrid = (out_size + 255)/256;

  const float* in[NIN];
  bool dict_ok = (n_in == NIN);
  if (dict_ok) for (int i=0;i<NIN;i++) if (in_sizes[i] != dsz[i]) { dict_ok=false; break; }
  if (dict_ok){
    for (int i=0;i<NIN;i++) in[i] = (const float*)d_in[i];
  } else {
    bool alpha_ok = (n_in == NIN);
    if (alpha_ok) for (int i=0;i<NIN;i++) if (in_sizes[i] != dsz[a2d[i]]) { alpha_ok=false; break; }
    if (alpha_ok){
      for (int i=0;i<NIN;i++) in[a2d[i]] = (const float*)d_in[i];
    } else {
      write_code_kernel<<<ogrid, 256, 0, stream>>>(dout, out_size, 5000.f + (float)n_in);
      return;
    }
  }

  const float* x      = in[0];
  const float* g1     = in[1];
  const float* b1     = in[2];
  const float* w_qkv  = in[3];
  const float* w_proj = in[4];
  const float* b_proj = in[5];
  const float* g2     = in[6];
  const float* b2     = in[7];
  const float* w_fc1  = in[8];
  const float* b_fc1  = in[9];
  const float* w_fc2  = in[10];
  const float* b_fc2  = in[11];
  const float* g3     = in[12];
  const float* b3     = in[13];
  const float* w_cqkv = in[14];
  const float* w_cproj= in[15];
  const float* b_cproj= in[16];
  const float* g4     = in[17];
  const float* b4     = in[18];
  const float* w_cfc1 = in[19];
  const float* b_cfc1 = in[20];
  const float* w_cfc2 = in[21];
  const float* b_cfc2 = in[22];

  char* ws = (char*)d_ws;
  const size_t TC2 = (size_t)T_*C_*2;          // 38,731,776 B
  const size_t NEED = 4*TC2 + 4096;
  if (ws_size < NEED){
    write_code_kernel<<<ogrid, 256, 0, stream>>>(dout, out_size,
        7000.f + (float)(ws_size >> 20));
    return;
  }

  // slabs: A = h1 -> o -> h2 -> channel scratch; B = q -> x2 -> x3;
  //        C+D = k,v -> hidh -> smalls
  bf16* h_buf   = (bf16*)(ws);
  bf16* o_buf   = (bf16*)(ws);
  bf16* q_buf   = (bf16*)(ws + TC2);
  bf16* k_buf   = (bf16*)(ws + 2*TC2);
  bf16* v_buf   = (bf16*)(ws + 3*TC2);
  bf16* x2_buf  = (bf16*)(ws + TC2);
  bf16* hidh    = (bf16*)(ws + 2*TC2);
  float* x3     = (float*)(ws + TC2);
  char* sm = ws + 2*TC2;
  float* h3  = (float*)sm; sm += (size_t)T_*32*4;
  float* cq  = (float*)sm; sm += (size_t)CSZ_*4;   // cq,ck,cv contiguous
  float* ck  = (float*)sm; sm += (size_t)CSZ_*4;
  float* cv  = (float*)sm; sm += (size_t)CSZ_*4;
  float* co  = (float*)sm; sm += (size_t)B_*32*CN_*4;
  float* co2 = (float*)sm; sm += (size_t)B_*32*CN_*4;
  float* x4  = (float*)sm; sm += (size_t)T_*32*4;
  float* h4  = (float*)sm; sm += (size_t)T_*32*4;
  float* chid = (float*)sm;
  // channel-GEMM scratch in slab A (dead after fc1 half2)
  u16* tall  = (u16*)(ws);                      // 4096*224*2 = 1.84 MB
  u16* wcq_b = (u16*)(ws + 2*1024*1024);        // 588*224*2 = 263 KB
  u16* co_b  = (u16*)(ws + 3*1024*1024);        // 1.84 MB
  u16* wcp_b = (u16*)(ws + 5*1024*1024);        // 88 KB

  // 1. h1 = LN(x)
  ln768_kernel<true><<<T_, 256, 0, stream>>>(x, g1, b1, h_buf);
  // 2. qkv (MFMA)
  gemm_mfma<0,false><<<dim3(T_/64, 2304/64), 256, 0, stream>>>((const u16*)h_buf,
      w_qkv, nullptr, nullptr, nullptr, nullptr, q_buf, k_buf, v_buf, T_, 3*C_, C_, C_);
  // 3. attention (MFMA) -> o
  attn_kernel<<<B_*H_, 256, 0, stream>>>((const u16*)q_buf, (const u16*)k_buf,
      (const u16*)v_buf, o_buf);
  // 4. x2 = x + o @ w_proj^T + b_proj
  gemm_mfma<1,false><<<dim3(T_/64, C_/64), 256, 0, stream>>>((const u16*)o_buf,
      w_proj, b_proj, x, x2_buf, nullptr, nullptr, nullptr, nullptr, T_, C_, C_, C_);
  // 5. h2 = LN(x2)
  ln768_kernel<false><<<T_, 256, 0, stream>>>(x2_buf, g2, b2, h_buf);
  // 6-9. fc1 (MFMA) + fc2 (MFMA, N=32) in two K-halves
  for (int half=0; half<2; half++){
    gemm_mfma<2,false><<<dim3(T_/64, 1536/64), 256, 0, stream>>>((const u16*)h_buf,
        w_fc1 + (size_t)half*1536*C_, b_fc1 + half*1536, nullptr,
        hidh, nullptr, nullptr, nullptr, nullptr, T_, 1536, C_, C_);
    if (half==0)
      gemm_mfma<3,false><<<dim3(T_/64, 1), 256, 0, stream>>>((const u16*)hidh,
          w_fc2, b_fc2, nullptr, nullptr, x3, nullptr, nullptr, nullptr,
          T_, OUT_, 1536, MH_);
    else
      gemm_mfma<4,false><<<dim3(T_/64, 1), 256, 0, stream>>>((const u16*)hidh,
          w_fc2 + 1536, nullptr, nullptr, nullptr, x3, nullptr, nullptr, nullptr,
          T_, OUT_, 1536, MH_);
  }
  // 10. h3 = LN(x3)
  ln32_kernel<<<(T_*32)/256, 256, 0, stream>>>(x3, g3, b3, h3);
  // 11. channel qkv as one batched MFMA GEMM (M=4096, N=588, K=224)
  pack_tall_kernel<<<(4096*KP_+255)/256, 256, 0, stream>>>(h3, tall);
  pack_w_kernel<<<(588*KP_+255)/256, 256, 0, stream>>>(w_cqkv, wcq_b, 588, CN_);
  gemm_mfma<5,true><<<dim3(4096/64, 10), 256, 0, stream>>>(tall, wcq_b,
      nullptr, nullptr, nullptr, cq, nullptr, nullptr, nullptr, 4096, 588, KP_, KP_);
  // 12. channel attention
  cattn_kernel<<<B_*CHH_, 64, 0, stream>>>(cq, ck, cv, co);
  // 13. channel proj as one MFMA GEMM (M=4096, N=196, K=224)
  pack_co_kernel<<<(4096*KP_+255)/256, 256, 0, stream>>>(co, co_b);
  pack_w_kernel<<<(196*KP_+255)/256, 256, 0, stream>>>(w_cproj, wcp_b, CN_, CN_);
  gemm_mfma<3,true><<<dim3(4096/64, 4), 256, 0, stream>>>(co_b, wcp_b,
      b_cproj, nullptr, nullptr, co2, nullptr, nullptr, nullptr, 4096, CN_, KP_, KP_);
  // 14. x4 = x3 + concat([cls, co2^T])
  concat_add_kernel<<<(T_*32)/256, 256, 0, stream>>>(x3, h3, co2, x4);
  // 15. h4 = LN(x4)
  ln32_kernel<<<(T_*32)/256, 256, 0, stream>>>(x4, g4, b4, h4);
  // 16. chid = gelu(h4 @ w_cfc1^T + b_cfc1)
  cfc1_kernel<<<(T_*128)/256, 256, 0, stream>>>(h4, w_cfc1, b_cfc1, chid);
  // 17. out = x4 + chid @ w_cfc2^T + b_cfc2  (fp32 out)
  cfc2_kernel<<<(T_*32)/256, 256, 0, stream>>>(chid, w_cfc2, b_cfc2, x4, dout);
}